// Round 9
// baseline (430.722 us; speedup 1.0000x reference)
//
#include <hip/hip_runtime.h>
#include <hip/hip_bf16.h>

#define VOCAB 12149
#define EMB 50
#define TAGS 9
#define HID 128
#define START_TOK 7
#define BSZ 256
#define TLEN 512

typedef _Float16 f16x2 __attribute__((ext_vector_type(2)));

__device__ __forceinline__ float tanh_fast(float x) {
  float e = __expf(2.0f * x);
  return 1.0f - 2.0f * __builtin_amdgcn_rcpf(e + 1.0f);
}

template<int CTRL>
__device__ __forceinline__ float dpp_mov(float x) {
  return __int_as_float(__builtin_amdgcn_update_dpp(
      0, __float_as_int(x), CTRL, 0xF, 0xF, true));
}
#define DPP_XOR1 0xB1   // quad_perm [1,0,3,2]
#define DPP_XOR2 0x4E   // quad_perm [2,3,0,1]

// exw[v][j] = sum_e emb[v][e] * enc_Wx[e][j] + enc_b[j]
__global__ __launch_bounds__(128) void exw_kernel(
    const float* __restrict__ emb, const float* __restrict__ Wx,
    const float* __restrict__ bv, float* __restrict__ exw)
{
  __shared__ float wx_s[EMB * HID];
  __shared__ float emb_s[8 * EMB];
  const int tid = threadIdx.x;
  const int v0 = blockIdx.x * 8;
  for (int idx = tid; idx < EMB * HID; idx += 128) wx_s[idx] = Wx[idx];
  for (int idx = tid; idx < 8 * EMB; idx += 128) {
    int r = idx / EMB;
    int e = idx - r * EMB;
    int v = v0 + r;
    emb_s[idx] = (v < VOCAB) ? emb[v * EMB + e] : 0.0f;
  }
  __syncthreads();
  const float bj = bv[tid];
  for (int r = 0; r < 8; ++r) {
    int v = v0 + r;
    if (v >= VOCAB) break;
    float acc = bj;
#pragma unroll
    for (int e = 0; e < EMB; ++e) acc += emb_s[r * EMB + e] * wx_s[e * HID + tid];
    exw[v * HID + tid] = acc;
  }
}

// One WG (128 thr = 2 waves) per batch row. Thread tid -> (q = tid&3 k-quarter,
// g = tid>>2 output quad). Reads h[32q..32q+31] as 8 ds_read_b128 with slot
// rotation (r+2q)&7 -> banks 4c+8q, conflict-free. acc[m] <-> output 4g+(m^q);
// 3-DPP quad reduce-scatter leaves lane owning h[tid]. One 2-wave barrier/step.
__global__ __launch_bounds__(128, 1) void rnn_kernel(
    const int* __restrict__ inputs, const int* __restrict__ labels,
    const float* __restrict__ exw,
    const float* __restrict__ encWh,
    const float* __restrict__ dembG, const float* __restrict__ decWx,
    const float* __restrict__ decWh, const float* __restrict__ decb,
    unsigned short* __restrict__ hws16)
{
  __shared__ __align__(16) float h_s[2][HID];
  __shared__ __align__(16) float dxw_s[TAGS * HID];
  __shared__ int tok_s[TLEN];
  __shared__ int lab_s[TLEN];

  const int tid = threadIdx.x;    // 0..127
  const int q = tid & 3;          // k-quarter
  const int jq = tid & ~3;        // quad's base output column (= 4*(tid>>2))
  const int bidx = blockIdx.x;

  for (int idx = tid; idx < TLEN; idx += 128) {
    tok_s[idx] = inputs[bidx * TLEN + idx];
    lab_s[idx] = labels[bidx * TLEN + idx];
  }
  for (int task = tid; task < TAGS * HID; task += 128) {
    int tag = task >> 7;
    int j2 = task & 127;
    float acc = decb[j2];
#pragma unroll
    for (int e = 0; e < EMB; ++e) acc += dembG[tag * EMB + e] * decWx[e * HID + j2];
    dxw_s[task] = acc;
  }
  h_s[0][tid] = 0.0f;

  // ---- encoder weights: wv[r][c][m] = Wh[32q + 4*((r+2q)&7) + c][jq + (m^q)]
  // loaded as float4 rows with static component permute (m^q).
  float wv[8][4][4];
#pragma unroll
  for (int r = 0; r < 8; ++r) {
    const int kb = 32 * q + 4 * ((r + 2 * q) & 7);
#pragma unroll
    for (int c = 0; c < 4; ++c) {
      const float4 wr = *(const float4*)&encWh[(kb + c) * HID + jq];
      const float wc[4] = {wr.x, wr.y, wr.z, wr.w};
#pragma unroll
      for (int m = 0; m < 4; ++m) wv[r][c][m] = wc[m ^ q];
    }
  }
  __syncthreads();

  const float* exw_i = exw + tid;
  int cur = 0;

  float xv0 = exw_i[tok_s[0] * HID];
  float xv1 = exw_i[tok_s[1] * HID];
  float xv2 = exw_i[tok_s[2] * HID];
  float xv3 = exw_i[tok_s[3] * HID];

  // ======== encoder ========
#pragma unroll 4
  for (int t = 0; t < TLEN; ++t) {
    int tn = (t + 4 < TLEN) ? t + 4 : TLEN - 1;
    float xvn = exw_i[tok_s[tn] * HID];

    const float* hb = &h_s[cur][32 * q];
    float a0 = 0.f, a1 = 0.f, a2 = 0.f, a3 = 0.f;
#pragma unroll
    for (int r = 0; r < 8; ++r) {
      const float4 hv = *(const float4*)&hb[4 * ((r + 2 * q) & 7)];
      a0 += hv.x * wv[r][0][0]; a1 += hv.x * wv[r][0][1];
      a2 += hv.x * wv[r][0][2]; a3 += hv.x * wv[r][0][3];
      a0 += hv.y * wv[r][1][0]; a1 += hv.y * wv[r][1][1];
      a2 += hv.y * wv[r][1][2]; a3 += hv.y * wv[r][1][3];
      a0 += hv.z * wv[r][2][0]; a1 += hv.z * wv[r][2][1];
      a2 += hv.z * wv[r][2][2]; a3 += hv.z * wv[r][2][3];
      a0 += hv.w * wv[r][3][0]; a1 += hv.w * wv[r][3][1];
      a2 += hv.w * wv[r][3][2]; a3 += hv.w * wv[r][3][3];
    }
    // quad reduce-scatter: lane ends with output jq + q = tid
    a0 += dpp_mov<DPP_XOR1>(a1);
    a2 += dpp_mov<DPP_XOR1>(a3);
    a0 += dpp_mov<DPP_XOR2>(a2);
    float hn = tanh_fast(a0 + xv0);
    h_s[cur ^ 1][tid] = hn;
    __syncthreads();
    cur ^= 1;
    xv0 = xv1; xv1 = xv2; xv2 = xv3; xv3 = xvn;
  }

  // ---- decoder weights (same registers/layout) ----
#pragma unroll
  for (int r = 0; r < 8; ++r) {
    const int kb = 32 * q + 4 * ((r + 2 * q) & 7);
#pragma unroll
    for (int c = 0; c < 4; ++c) {
      const float4 wr = *(const float4*)&decWh[(kb + c) * HID + jq];
      const float wc[4] = {wr.x, wr.y, wr.z, wr.w};
#pragma unroll
      for (int m = 0; m < 4; ++m) wv[r][c][m] = wc[m ^ q];
    }
  }

  // ======== decoder ========
  unsigned short* hrow = hws16 + (size_t)(bidx * TLEN) * HID + tid;
  float xvD = dxw_s[START_TOK * HID + tid];
#pragma unroll 2
  for (int t = 0; t < TLEN; ++t) {
    int labn = lab_s[t];                       // dec_in[t+1] = label[t]
    float xvDn = dxw_s[labn * HID + tid];      // prefetch next step's xv

    const float* hb = &h_s[cur][32 * q];
    float a0 = 0.f, a1 = 0.f, a2 = 0.f, a3 = 0.f;
#pragma unroll
    for (int r = 0; r < 8; ++r) {
      const float4 hv = *(const float4*)&hb[4 * ((r + 2 * q) & 7)];
      a0 += hv.x * wv[r][0][0]; a1 += hv.x * wv[r][0][1];
      a2 += hv.x * wv[r][0][2]; a3 += hv.x * wv[r][0][3];
      a0 += hv.y * wv[r][1][0]; a1 += hv.y * wv[r][1][1];
      a2 += hv.y * wv[r][1][2]; a3 += hv.y * wv[r][1][3];
      a0 += hv.z * wv[r][2][0]; a1 += hv.z * wv[r][2][1];
      a2 += hv.z * wv[r][2][2]; a3 += hv.z * wv[r][2][3];
      a0 += hv.w * wv[r][3][0]; a1 += hv.w * wv[r][3][1];
      a2 += hv.w * wv[r][3][2]; a3 += hv.w * wv[r][3][3];
    }
    a0 += dpp_mov<DPP_XOR1>(a1);
    a2 += dpp_mov<DPP_XOR1>(a3);
    a0 += dpp_mov<DPP_XOR2>(a2);
    float hn = tanh_fast(a0 + xvD);
    h_s[cur ^ 1][tid] = hn;
    hrow[(size_t)t * HID] =
        __builtin_bit_cast(unsigned short, (_Float16)hn);
    __syncthreads();
    cur ^= 1;
    xvD = xvDn;
  }
}

// out[t][o] = h[t] @ W + b; h stored as 128 f16 per row
__global__ __launch_bounds__(256) void proj_kernel(
    const unsigned short* __restrict__ hws16, const float* __restrict__ W,
    const float* __restrict__ bout, float* __restrict__ out)
{
  __shared__ float Wt_s[TAGS][HID];
  __shared__ float bo_s[TAGS];
  const int tid = threadIdx.x;
  for (int idx = tid; idx < TAGS * HID; idx += 256) {
    int o = idx >> 7;
    int j2 = idx & 127;
    Wt_s[o][j2] = W[j2 * TAGS + o];
  }
  if (tid < TAGS) bo_s[tid] = bout[tid];
  __syncthreads();

  const int gt = blockIdx.x * 256 + tid;       // 0 .. B*T-1
  const uint2* hrow = (const uint2*)(hws16 + (size_t)gt * HID);
  float acc[TAGS];
#pragma unroll
  for (int o = 0; o < TAGS; ++o) acc[o] = bo_s[o];
#pragma unroll
  for (int c = 0; c < 32; ++c) {               // 32 chunks x 4 f16 = 128 = HID
    uint2 u = hrow[c];
    f16x2 p0 = __builtin_bit_cast(f16x2, u.x);
    f16x2 p1 = __builtin_bit_cast(f16x2, u.y);
    float h0 = (float)p0.x, h1 = (float)p0.y;
    float h2v = (float)p1.x, h3 = (float)p1.y;
#pragma unroll
    for (int o = 0; o < TAGS; ++o) {
      const float* wr = &Wt_s[o][4 * c];
      acc[o] += h0 * wr[0] + h1 * wr[1] + h2v * wr[2] + h3 * wr[3];
    }
  }
  float* op = &out[(size_t)gt * TAGS];
#pragma unroll
  for (int o = 0; o < TAGS; ++o) op[o] = acc[o];
}

extern "C" void kernel_launch(void* const* d_in, const int* in_sizes, int n_in,
                              void* d_out, int out_size, void* d_ws, size_t ws_size,
                              hipStream_t stream) {
  const int* inputs   = (const int*)d_in[0];
  const int* labels   = (const int*)d_in[1];
  const float* emb    = (const float*)d_in[2];
  const float* encWx  = (const float*)d_in[3];
  const float* encWh  = (const float*)d_in[4];
  const float* encb   = (const float*)d_in[5];
  const float* demb   = (const float*)d_in[6];
  const float* decWx  = (const float*)d_in[7];
  const float* decWh  = (const float*)d_in[8];
  const float* decb   = (const float*)d_in[9];
  const float* W      = (const float*)d_in[10];
  const float* bo     = (const float*)d_in[11];
  float* out = (float*)d_out;

  const size_t exw_floats = (size_t)VOCAB * HID;                 // 6.22 MB
  float* exw = (float*)d_ws;
  unsigned short* hws16 = (unsigned short*)((float*)d_ws + exw_floats);
  // needed: 6.22 MB + B*T*HID*2 = 23 MB total (ws >= 40 MB proven in round 6)

  exw_kernel<<<(VOCAB + 7) / 8, 128, 0, stream>>>(emb, encWx, encb, exw);
  rnn_kernel<<<BSZ, 128, 0, stream>>>(inputs, labels, exw, encWh,
                                      demb, decWx, decWh, decb, hws16);
  proj_kernel<<<(BSZ * TLEN) / 256, 256, 0, stream>>>(hws16, W, bo, out);
}